// Round 6
// baseline (167.065 us; speedup 1.0000x reference)
//
#include <hip/hip_runtime.h>
#include <hip/hip_bf16.h>

#define HEADS 4
#define ODIM 64
#define HD 256          // HEADS*ODIM
#define NEG_SLOPE 0.2f
#define SPLITS 4
#define BJ 128          // j-chunk

typedef __attribute__((ext_vector_type(8))) short bf16x8;
typedef __attribute__((ext_vector_type(4))) float floatx4;
typedef __attribute__((ext_vector_type(2))) float floatx2;

// ============ pack x and W -> bf16 hi/lo MFMA fragments + bit-pack adj (one launch) ============
// A-frag layout: frag[(mc*Kc + kc)][lane][8], lane=(l16,q): A[m=mc*16+l16][k=kc*32+q*8+p]
// B-frag layout: frag[(nc*Kc + kc)][lane][8], lane=(l16,q): B[k=kc*32+q*8+p][n=nc*16+l16]
// adjP layout: bit (j&63) of adjP[i*(n/64) + (j>>6)] = (adj[i][j] > 0)
__global__ __launch_bounds__(256) void pack_xw(const float* __restrict__ x,
                                               const float* __restrict__ W,
                                               const int* __restrict__ adj,
                                               __hip_bfloat16* __restrict__ xh,
                                               __hip_bfloat16* __restrict__ xl,
                                               __hip_bfloat16* __restrict__ wh,
                                               __hip_bfloat16* __restrict__ wl,
                                               unsigned long long* __restrict__ adjP,
                                               int K, int n, int nxb, int nwb) {
    const int b = blockIdx.x;
    const int Kc = K >> 5;
    if (b < nxb) {
        const int g = b * 256 + threadIdx.x;
        const int lane = g & 63, frag = g >> 6;
        const int kc = frag % Kc, mc = frag / Kc;
        const int l16 = lane & 15, q = lane >> 4;
        const float* src = x + (size_t)(mc * 16 + l16) * K + kc * 32 + q * 8;
        const float4 v0 = *(const float4*)src;
        const float4 v1 = *(const float4*)(src + 4);
        const float vv[8] = {v0.x, v0.y, v0.z, v0.w, v1.x, v1.y, v1.z, v1.w};
        union { __hip_bfloat16 b[8]; bf16x8 v; } H, L;
        #pragma unroll
        for (int p = 0; p < 8; ++p) {
            H.b[p] = __float2bfloat16(vv[p]);
            L.b[p] = __float2bfloat16(vv[p] - __bfloat162float(H.b[p]));
        }
        *(bf16x8*)&xh[(size_t)frag * 512 + lane * 8] = H.v;
        *(bf16x8*)&xl[(size_t)frag * 512 + lane * 8] = L.v;
    } else if (b < nxb + nwb) {
        const int g = (b - nxb) * 256 + threadIdx.x;
        const int lane = g & 63, frag = g >> 6;
        const int kc = frag % Kc, nc = frag / Kc;
        const int l16 = lane & 15, q = lane >> 4;
        union { __hip_bfloat16 b[8]; bf16x8 v; } H, L;
        #pragma unroll
        for (int p = 0; p < 8; ++p) {
            const float w = W[(size_t)(kc * 32 + q * 8 + p) * HD + nc * 16 + l16];
            H.b[p] = __float2bfloat16(w);
            L.b[p] = __float2bfloat16(w - __bfloat162float(H.b[p]));
        }
        *(bf16x8*)&wh[(size_t)frag * 512 + lane * 8] = H.v;
        *(bf16x8*)&wl[(size_t)frag * 512 + lane * 8] = L.v;
    } else {
        // ---- adj bit-pack: 256 grid-strided blocks (1/CU). Task = ROW-QUARTER
        // (R5 bug: task was a whole row but only 16/64 segments loaded -> 3/4 of
        // edges dropped). n*4 quarter-tasks over 1024 waves; each task issues all
        // 16 seg-loads (256B each) before any ballot -> 16 outstanding/wave,
        // BW-bound (~6 TB/s), full column coverage.
        const int bb = b - nxb - nwb;          // 0..255
        const int wv = threadIdx.x >> 6, ln = threadIdx.x & 63;
        const int gw = bb * 4 + wv;            // global wave id, 0..1023
        const int segs = n >> 6;               // 64-col segments per row
        for (int t = gw; t < n * 4; t += 1024) {
            const int row = t >> 2, qq = t & 3;
            const int* ar = adj + (size_t)row * n + (size_t)qq * 16 * 64;
            unsigned long long* dst = adjP + (size_t)row * segs + qq * 16;
            int v[16];
            #pragma unroll
            for (int s = 0; s < 16; ++s) v[s] = ar[s * 64 + ln];
            #pragma unroll
            for (int s = 0; s < 16; ++s) {
                const unsigned long long m = __ballot(v[s] > 0);
                if (ln == 0) dst[s] = m;
            }
        }
    }
}

// ============ fused GEMM: h = x@W (hi/lo bf16 MFMA) + E epilogue + B-frag pack of h ============
// block = 128 thr (2 waves, 16 rows each), grid (n/32, HEADS) = 512 blocks (2/CU).
// E output in per-head layouts: Es[h*n+i] = (e^ps, e^.2ps), Ed[h*n+i] = (e^pd, e^.2pd)
// so aggregate's per-lane dst-exp slice is a contiguous 64B load.
__global__ __launch_bounds__(128) void gemm_fused(
    const __hip_bfloat16* __restrict__ xh, const __hip_bfloat16* __restrict__ xl,
    const __hip_bfloat16* __restrict__ wh, const __hip_bfloat16* __restrict__ wl,
    const float* __restrict__ att, float2* __restrict__ Es, float2* __restrict__ Ed,
    __hip_bfloat16* __restrict__ hbB, int n, int K) {

    __shared__ __hip_bfloat16 T[64][40];   // h^T tile [d][j(32)], stride 40 (16B-aligned rows)

    const int tid = threadIdx.x, wave = tid >> 6, lane = tid & 63;
    const int q = lane >> 4, l16 = lane & 15;
    const int m0 = blockIdx.x * 32;
    const int head = blockIdx.y;
    const int Kc = K >> 5;
    const int mc = (m0 >> 4) + wave;

    floatx4 acc[4] = {{0.f,0.f,0.f,0.f},{0.f,0.f,0.f,0.f},{0.f,0.f,0.f,0.f},{0.f,0.f,0.f,0.f}};

    const __hip_bfloat16* Axh = xh + (size_t)mc * Kc * 512 + lane * 8;
    const __hip_bfloat16* Axl = xl + (size_t)mc * Kc * 512 + lane * 8;
    const __hip_bfloat16* Bwh = wh + lane * 8;
    const __hip_bfloat16* Bwl = wl + lane * 8;
    #pragma unroll 2
    for (int kc = 0; kc < Kc; ++kc) {
        const bf16x8 ah = *(const bf16x8*)(Axh + (size_t)kc * 512);
        const bf16x8 al = *(const bf16x8*)(Axl + (size_t)kc * 512);
        bf16x8 bh[4], bl[4];
        #pragma unroll
        for (int nt = 0; nt < 4; ++nt) {
            const size_t fo = (size_t)((head * 4 + nt) * Kc + kc) * 512;
            bh[nt] = *(const bf16x8*)(Bwh + fo);
            bl[nt] = *(const bf16x8*)(Bwl + fo);
        }
        // pass-major order: dependency distance 4 between same-acc MFMAs
        #pragma unroll
        for (int nt = 0; nt < 4; ++nt)
            acc[nt] = __builtin_amdgcn_mfma_f32_16x16x32_bf16(ah, bh[nt], acc[nt], 0, 0, 0);
        #pragma unroll
        for (int nt = 0; nt < 4; ++nt)
            acc[nt] = __builtin_amdgcn_mfma_f32_16x16x32_bf16(ah, bl[nt], acc[nt], 0, 0, 0);
        #pragma unroll
        for (int nt = 0; nt < 4; ++nt)
            acc[nt] = __builtin_amdgcn_mfma_f32_16x16x32_bf16(al, bh[nt], acc[nt], 0, 0, 0);
    }

    // ---- E epilogue: e_src/e_dst row sums via shuffle over the 16-lane group ----
    float as_v[4], ad_v[4];
    #pragma unroll
    for (int nt = 0; nt < 4; ++nt) {
        as_v[nt] = att[head * 2 * ODIM + nt * 16 + l16];
        ad_v[nt] = att[head * 2 * ODIM + ODIM + nt * 16 + l16];
    }
    #pragma unroll
    for (int r = 0; r < 4; ++r) {
        float ps = 0.f, pd = 0.f;
        #pragma unroll
        for (int nt = 0; nt < 4; ++nt) {
            ps = fmaf(acc[nt][r], as_v[nt], ps);
            pd = fmaf(acc[nt][r], ad_v[nt], pd);
        }
        #pragma unroll
        for (int m = 1; m <= 8; m <<= 1) {
            ps += __shfl_xor(ps, m, 64);
            pd += __shfl_xor(pd, m, 64);
        }
        if (l16 == 0) {
            const int i = m0 + wave * 16 + q * 4 + r;
            Es[head * n + i] = make_float2(__expf(ps), __expf(NEG_SLOPE * ps));
            Ed[head * n + i] = make_float2(__expf(pd), __expf(NEG_SLOPE * pd));
        }
    }

    // ---- write h tile transposed to LDS as bf16 ----
    #pragma unroll
    for (int nt = 0; nt < 4; ++nt) {
        union { __hip_bfloat16 b[4]; uint2 u; } pk;
        #pragma unroll
        for (int r = 0; r < 4; ++r) pk.b[r] = __float2bfloat16(acc[nt][r]);
        *(uint2*)&T[nt * 16 + l16][wave * 16 + q * 4] = pk.u;
    }
    __syncthreads();

    // ---- emit packed B-frags of h: frag[(head*(n/32) + j32)*4 + nt][lane][8] ----
    #pragma unroll
    for (int ffi = 0; ffi < 2; ++ffi) {
        const int f = wave + ffi * 2;   // nt
        const bf16x8 v = *(const bf16x8*)&T[f * 16 + l16][q * 8];
        const size_t frag = ((size_t)head * (n >> 5) + (m0 >> 5)) * 4 + f;
        *(bf16x8*)&hbB[frag * 512 + lane * 8] = v;
    }
}

// ============ aggregate: out_split[s][i][h*64+d] = sum_j P[i,j,h] h[j,h,d] ============
// BARRIER-FREE, LDS-FREE (R4 structure, verified correct). Each wave (= head) is
// autonomous: per-lane adj mask bits from bit-packed adjP registers, dst-exps from
// per-head Ed[] as contiguous 64B loads, hbB frags register-double-buffered one
// 32-j step ahead. No __shared__, no __syncthreads.
__global__ __launch_bounds__(256, 3) void aggregate(
    const unsigned int* __restrict__ adjP32, const float2* __restrict__ Es,
    const float2* __restrict__ Ed, const __hip_bfloat16* __restrict__ hbB,
    float* __restrict__ outsp, float* __restrict__ densp, int n, int KR) {

    const int tid = threadIdx.x;
    const int wave = tid >> 6, lane = tid & 63;
    const int q = lane >> 4, l16 = lane & 15, q8 = q * 8;
    const int i0 = blockIdx.x * 32;
    const int K0 = blockIdx.y * KR;

    // src-side exps for this lane's two rows (head = wave)
    floatx2 es12[2];
    #pragma unroll
    for (int mt = 0; mt < 2; ++mt) {
        const float2 e = Es[(size_t)wave * n + i0 + mt * 16 + l16];
        es12[mt][0] = e.x; es12[mt][1] = e.y;
    }

    // ones-column B-frag for MFMA-based denominator
    union { short s[8]; bf16x8 v; } bones;
    #pragma unroll
    for (int p = 0; p < 8; ++p) bones.s[p] = (l16 == 0) ? (short)0x3F80 : (short)0;

    floatx4 acc[2][4];
    floatx4 accd[2];
    #pragma unroll
    for (int mt = 0; mt < 2; ++mt) {
        accd[mt] = (floatx4){0.f, 0.f, 0.f, 0.f};
        #pragma unroll
        for (int nt = 0; nt < 4; ++nt) acc[mt][nt] = (floatx4){0.f, 0.f, 0.f, 0.f};
    }

    // per-lane row mask pointers (rows i0+l16 and i0+16+l16; lanes 16-63 broadcast)
    const unsigned int* aR0 = adjP32 + (size_t)(i0 + l16) * (n >> 5);
    const unsigned int* aR1 = adjP32 + (size_t)(i0 + 16 + l16) * (n >> 5);
    const float2* edp = Ed + (size_t)wave * n;
    const __hip_bfloat16* hb = hbB + ((size_t)wave * (n >> 5) * 4) * 512 + lane * 8;

    const int ksBase = K0 >> 5;       // global 32-j step index base
    const int nks = KR >> 5;          // steps per block (32 @ SPLITS=4)
    const int NG = nks >> 2;          // uint4 mask groups

    // depth-1 register pipeline, statically double-buffered (all indices compile-time)
    float4 edb[2][4];
    bf16x8 hbb[2][4];
    auto ldks = [&](int s, int b) {
        const float4* ev = (const float4*)(edp + (size_t)s * 32 + q8);
        #pragma unroll
        for (int p = 0; p < 4; ++p) edb[b][p] = ev[p];
        #pragma unroll
        for (int nt = 0; nt < 4; ++nt)
            hbb[b][nt] = *(const bf16x8*)(hb + (size_t)(s * 4 + nt) * 512);
    };

    ldks(ksBase, 0);
    uint4 a0c = *(const uint4*)&aR0[ksBase];
    uint4 a1c = *(const uint4*)&aR1[ksBase];

    for (int g = 0; g < NG; ++g) {
        const int gn = (g + 1 < NG) ? g + 1 : 0;           // tail clamp: dummy reload
        const uint4 a0n = *(const uint4*)&aR0[ksBase + gn * 4];
        const uint4 a1n = *(const uint4*)&aR1[ksBase + gn * 4];
        #pragma unroll
        for (int k4 = 0; k4 < 4; ++k4) {
            const int s = ksBase + g * 4 + k4;
            const int sn = (g * 4 + k4 + 1 < nks) ? s + 1 : ksBase;
            ldks(sn, (k4 + 1) & 1);                        // prefetch next 32-j step
            const int cb = k4 & 1;
            const unsigned int w0 = k4 == 0 ? a0c.x : k4 == 1 ? a0c.y : k4 == 2 ? a0c.z : a0c.w;
            const unsigned int w1 = k4 == 0 ? a1c.x : k4 == 1 ? a1c.y : k4 == 2 ? a1c.z : a1c.w;
            #pragma unroll
            for (int mt = 0; mt < 2; ++mt) {
                const unsigned int wmt = mt ? w1 : w0;
                union { unsigned int u[4]; bf16x8 v; } af;
                #pragma unroll
                for (int p = 0; p < 4; ++p) {
                    const float4 e = edb[cb][p];           // (e^pd,e^.2pd) for j=s*32+q8+2p, +1
                    const float wa = fmaxf(es12[mt][0] * e.x, es12[mt][1] * e.y);
                    const float wb = fmaxf(es12[mt][0] * e.z, es12[mt][1] * e.w);
                    const unsigned int sh = wmt >> (q8 + 2 * p);
                    const unsigned int mm = ((sh & 1u) ? 0xFFFFu : 0u) |
                                            ((sh & 2u) ? 0xFFFF0000u : 0u);
                    af.u[p] = __builtin_amdgcn_perm(__float_as_uint(wb), __float_as_uint(wa),
                                                    0x07060302u) & mm;
                }
                #pragma unroll
                for (int nt = 0; nt < 4; ++nt)
                    acc[mt][nt] = __builtin_amdgcn_mfma_f32_16x16x32_bf16(af.v, hbb[cb][nt], acc[mt][nt], 0, 0, 0);
                accd[mt] = __builtin_amdgcn_mfma_f32_16x16x32_bf16(af.v, bones.v, accd[mt], 0, 0, 0);
            }
        }
        a0c = a0n; a1c = a1n;
    }

    // ---- epilogue: disjoint per-split writes, no atomics ----
    const size_t sOut = (size_t)blockIdx.y * n * HD;
    #pragma unroll
    for (int mt = 0; mt < 2; ++mt)
        #pragma unroll
        for (int nt = 0; nt < 4; ++nt)
            #pragma unroll
            for (int r = 0; r < 4; ++r)
                outsp[sOut + (size_t)(i0 + mt * 16 + q * 4 + r) * HD + wave * ODIM + nt * 16 + l16] = acc[mt][nt][r];
    if (l16 == 0) {
        #pragma unroll
        for (int mt = 0; mt < 2; ++mt)
            #pragma unroll
            for (int r = 0; r < 4; ++r)
                densp[((size_t)blockIdx.y * n + i0 + mt * 16 + q * 4 + r) * HEADS + wave] = accd[mt][r];
    }
}

// ============ normalize: out = sum_s outsp / sum_s densp ============
__global__ __launch_bounds__(256) void normalize(const float* __restrict__ outsp,
                                                 const float* __restrict__ densp,
                                                 float* __restrict__ out, int n, int splits) {
    const int g = blockIdx.x * 256 + threadIdx.x;
    const int i = g >> 6;
    const int c4 = (g & 63) * 4;
    const int head = c4 >> 6;
    float den = 0.f;
    for (int s = 0; s < splits; ++s) den += densp[((size_t)s * n + i) * HEADS + head];
    float4 v = {0.f, 0.f, 0.f, 0.f};
    for (int s = 0; s < splits; ++s) {
        const float4 t = *(const float4*)&outsp[(size_t)s * n * HD + (size_t)i * HD + c4];
        v.x += t.x; v.y += t.y; v.z += t.z; v.w += t.w;
    }
    const float inv = 1.0f / den;
    v.x *= inv; v.y *= inv; v.z *= inv; v.w *= inv;
    *(float4*)&out[(size_t)i * HD + c4] = v;
}

extern "C" void kernel_launch(void* const* d_in, const int* in_sizes, int n_in,
                              void* d_out, int out_size, void* d_ws, size_t ws_size,
                              hipStream_t stream) {
    const float* x   = (const float*)d_in[0];
    const int*   adj = (const int*)d_in[1];
    const float* W   = (const float*)d_in[2];
    const float* att = (const float*)d_in[3];
    float* out = (float*)d_out;

    const int in_dim = in_sizes[2] / HD;   // 256
    const int n = in_sizes[0] / in_dim;    // 4096

    char* ws = (char*)d_ws;
    size_t off = 0;
    auto alloc = [&](size_t bytes) -> void* {
        void* p = ws + off; off += (bytes + 255) & ~(size_t)255; return p;
    };
    __hip_bfloat16* xh = (__hip_bfloat16*)alloc((size_t)n * in_dim * 2);
    __hip_bfloat16* xl = (__hip_bfloat16*)alloc((size_t)n * in_dim * 2);
    __hip_bfloat16* wh = (__hip_bfloat16*)alloc((size_t)in_dim * HD * 2);
    __hip_bfloat16* wl = (__hip_bfloat16*)alloc((size_t)in_dim * HD * 2);
    float2*         Es = (float2*)alloc((size_t)HEADS * n * 8);
    float2*         Ed = (float2*)alloc((size_t)HEADS * n * 8);
    __hip_bfloat16* hbB = (__hip_bfloat16*)alloc((size_t)n * HD * 2);
    unsigned long long* adjP = (unsigned long long*)alloc((size_t)n * (n >> 6) * 8);

    const size_t outB = (size_t)n * HD * 4, denB = (size_t)n * HEADS * 4;
    float* densp = (float*)alloc((size_t)SPLITS * denB);
    float* outsp = (float*)alloc((size_t)SPLITS * outB);

    const int nxb = (n / 16) * (in_dim / 32) * 64 / 256;
    const int nwb = (HD / 16) * (in_dim / 32) * 64 / 256;
    const int nab = 256;   // grid-strided streaming adj-pack blocks (1/CU)
    pack_xw<<<nxb + nwb + nab, 256, 0, stream>>>(x, W, adj, xh, xl, wh, wl, adjP, in_dim, n, nxb, nwb);
    gemm_fused<<<dim3(n / 32, HEADS), 128, 0, stream>>>(xh, xl, wh, wl, att, Es, Ed, hbB, n, in_dim);
    aggregate<<<dim3(n / 32, SPLITS), 256, 0, stream>>>((const unsigned int*)adjP, Es, Ed, hbB, outsp, densp, n, n / SPLITS);
    normalize<<<n * 64 / 256, 256, 0, stream>>>(outsp, densp, out, n, SPLITS);
}

// Round 7
// 165.694 us; speedup vs baseline: 1.0083x; 1.0083x over previous
//
#include <hip/hip_runtime.h>
#include <hip/hip_bf16.h>

#define HEADS 4
#define ODIM 64
#define HD 256          // HEADS*ODIM
#define NEG_SLOPE 0.2f
#define SPLITS 8

typedef __attribute__((ext_vector_type(8))) short bf16x8;
typedef __attribute__((ext_vector_type(4))) float floatx4;
typedef __attribute__((ext_vector_type(2))) float floatx2;

// ============ pack x and W -> bf16 hi/lo MFMA fragments (x/W only) ============
// A-frag layout: frag[(mc*Kc + kc)][lane][8], lane=(l16,q): A[m=mc*16+l16][k=kc*32+q*8+p]
// B-frag layout: frag[(nc*Kc + kc)][lane][8], lane=(l16,q): B[k=kc*32+q*8+p][n=nc*16+l16]
__global__ __launch_bounds__(256) void pack_xw(const float* __restrict__ x,
                                               const float* __restrict__ W,
                                               __hip_bfloat16* __restrict__ xh,
                                               __hip_bfloat16* __restrict__ xl,
                                               __hip_bfloat16* __restrict__ wh,
                                               __hip_bfloat16* __restrict__ wl,
                                               int K, int nxb) {
    const int b = blockIdx.x;
    const int Kc = K >> 5;
    if (b < nxb) {
        const int g = b * 256 + threadIdx.x;
        const int lane = g & 63, frag = g >> 6;
        const int kc = frag % Kc, mc = frag / Kc;
        const int l16 = lane & 15, q = lane >> 4;
        const float* src = x + (size_t)(mc * 16 + l16) * K + kc * 32 + q * 8;
        const float4 v0 = *(const float4*)src;
        const float4 v1 = *(const float4*)(src + 4);
        const float vv[8] = {v0.x, v0.y, v0.z, v0.w, v1.x, v1.y, v1.z, v1.w};
        union { __hip_bfloat16 b[8]; bf16x8 v; } H, L;
        #pragma unroll
        for (int p = 0; p < 8; ++p) {
            H.b[p] = __float2bfloat16(vv[p]);
            L.b[p] = __float2bfloat16(vv[p] - __bfloat162float(H.b[p]));
        }
        *(bf16x8*)&xh[(size_t)frag * 512 + lane * 8] = H.v;
        *(bf16x8*)&xl[(size_t)frag * 512 + lane * 8] = L.v;
    } else {
        const int g = (b - nxb) * 256 + threadIdx.x;
        const int lane = g & 63, frag = g >> 6;
        const int kc = frag % Kc, nc = frag / Kc;
        const int l16 = lane & 15, q = lane >> 4;
        union { __hip_bfloat16 b[8]; bf16x8 v; } H, L;
        #pragma unroll
        for (int p = 0; p < 8; ++p) {
            const float w = W[(size_t)(kc * 32 + q * 8 + p) * HD + nc * 16 + l16];
            H.b[p] = __float2bfloat16(w);
            L.b[p] = __float2bfloat16(w - __bfloat162float(H.b[p]));
        }
        *(bf16x8*)&wh[(size_t)frag * 512 + lane * 8] = H.v;
        *(bf16x8*)&wl[(size_t)frag * 512 + lane * 8] = L.v;
    }
}

// ============ fused GEMM: h = x@W + E epilogue + B-frag pack of h + adj bit-pack ============
// grid (n/32, HEADS+2), block 128. y<HEADS: GEMM (2 waves, 16 rows each, 512 blocks, 2/CU).
// y>=HEADS: adj bit-pack blocks (256 blocks x 2 waves) — the 64 MB adj stream overlaps
// the GEMM's compute phase instead of serializing in pack_xw (R6: +15 us serial cost).
// adjP layout: bit (j&63) of adjP[i*(n/64) + (j>>6)] = (adj[i][j] > 0)
__global__ __launch_bounds__(128) void gemm_fused(
    const __hip_bfloat16* __restrict__ xh, const __hip_bfloat16* __restrict__ xl,
    const __hip_bfloat16* __restrict__ wh, const __hip_bfloat16* __restrict__ wl,
    const float* __restrict__ att, const int* __restrict__ adj,
    float2* __restrict__ Es, float2* __restrict__ Ed,
    __hip_bfloat16* __restrict__ hbB, unsigned long long* __restrict__ adjP,
    int n, int K) {

    __shared__ __hip_bfloat16 T[64][40];   // h^T tile [d][j(32)], stride 40 (16B-aligned rows)

    if (blockIdx.y >= HEADS) {
        // ---- adj bit-pack: task = row-quarter (16 segs of 64 cols), all 16 loads
        // issued before any ballot -> 16 outstanding 256B loads/wave, BW-bound.
        const int bb = blockIdx.x + (blockIdx.y - HEADS) * (n >> 5);  // 0..255
        const int wv = threadIdx.x >> 6, ln = threadIdx.x & 63;
        const int gw = bb * 2 + wv;            // 0..511
        const int segs = n >> 6;
        for (int t = gw; t < n * 4; t += 512) {
            const int row = t >> 2, qq = t & 3;
            const int* ar = adj + (size_t)row * n + (size_t)qq * 1024;
            unsigned long long* dst = adjP + (size_t)row * segs + qq * 16;
            int v[16];
            #pragma unroll
            for (int s = 0; s < 16; ++s) v[s] = ar[s * 64 + ln];
            #pragma unroll
            for (int s = 0; s < 16; ++s) {
                const unsigned long long m = __ballot(v[s] > 0);
                if (ln == 0) dst[s] = m;
            }
        }
        return;
    }

    const int tid = threadIdx.x, wave = tid >> 6, lane = tid & 63;
    const int q = lane >> 4, l16 = lane & 15;
    const int m0 = blockIdx.x * 32;
    const int head = blockIdx.y;
    const int Kc = K >> 5;
    const int mc = (m0 >> 4) + wave;

    floatx4 acc[4] = {{0.f,0.f,0.f,0.f},{0.f,0.f,0.f,0.f},{0.f,0.f,0.f,0.f},{0.f,0.f,0.f,0.f}};

    const __hip_bfloat16* Axh = xh + (size_t)mc * Kc * 512 + lane * 8;
    const __hip_bfloat16* Axl = xl + (size_t)mc * Kc * 512 + lane * 8;
    const __hip_bfloat16* Bwh = wh + lane * 8;
    const __hip_bfloat16* Bwl = wl + lane * 8;
    #pragma unroll 2
    for (int kc = 0; kc < Kc; ++kc) {
        const bf16x8 ah = *(const bf16x8*)(Axh + (size_t)kc * 512);
        const bf16x8 al = *(const bf16x8*)(Axl + (size_t)kc * 512);
        bf16x8 bh[4], bl[4];
        #pragma unroll
        for (int nt = 0; nt < 4; ++nt) {
            const size_t fo = (size_t)((head * 4 + nt) * Kc + kc) * 512;
            bh[nt] = *(const bf16x8*)(Bwh + fo);
            bl[nt] = *(const bf16x8*)(Bwl + fo);
        }
        // pass-major order: dependency distance 4 between same-acc MFMAs
        #pragma unroll
        for (int nt = 0; nt < 4; ++nt)
            acc[nt] = __builtin_amdgcn_mfma_f32_16x16x32_bf16(ah, bh[nt], acc[nt], 0, 0, 0);
        #pragma unroll
        for (int nt = 0; nt < 4; ++nt)
            acc[nt] = __builtin_amdgcn_mfma_f32_16x16x32_bf16(ah, bl[nt], acc[nt], 0, 0, 0);
        #pragma unroll
        for (int nt = 0; nt < 4; ++nt)
            acc[nt] = __builtin_amdgcn_mfma_f32_16x16x32_bf16(al, bh[nt], acc[nt], 0, 0, 0);
    }

    // ---- E epilogue: e_src/e_dst row sums via shuffle over the 16-lane group ----
    float as_v[4], ad_v[4];
    #pragma unroll
    for (int nt = 0; nt < 4; ++nt) {
        as_v[nt] = att[head * 2 * ODIM + nt * 16 + l16];
        ad_v[nt] = att[head * 2 * ODIM + ODIM + nt * 16 + l16];
    }
    #pragma unroll
    for (int r = 0; r < 4; ++r) {
        float ps = 0.f, pd = 0.f;
        #pragma unroll
        for (int nt = 0; nt < 4; ++nt) {
            ps = fmaf(acc[nt][r], as_v[nt], ps);
            pd = fmaf(acc[nt][r], ad_v[nt], pd);
        }
        #pragma unroll
        for (int m = 1; m <= 8; m <<= 1) {
            ps += __shfl_xor(ps, m, 64);
            pd += __shfl_xor(pd, m, 64);
        }
        if (l16 == 0) {
            const int i = m0 + wave * 16 + q * 4 + r;
            Es[head * n + i] = make_float2(__expf(ps), __expf(NEG_SLOPE * ps));
            Ed[head * n + i] = make_float2(__expf(pd), __expf(NEG_SLOPE * pd));
        }
    }

    // ---- write h tile transposed to LDS as bf16 ----
    #pragma unroll
    for (int nt = 0; nt < 4; ++nt) {
        union { __hip_bfloat16 b[4]; uint2 u; } pk;
        #pragma unroll
        for (int r = 0; r < 4; ++r) pk.b[r] = __float2bfloat16(acc[nt][r]);
        *(uint2*)&T[nt * 16 + l16][wave * 16 + q * 4] = pk.u;
    }
    __syncthreads();

    // ---- emit packed B-frags of h: frag[(head*(n/32) + j32)*4 + nt][lane][8] ----
    #pragma unroll
    for (int ffi = 0; ffi < 2; ++ffi) {
        const int f = wave + ffi * 2;   // nt
        const bf16x8 v = *(const bf16x8*)&T[f * 16 + l16][q * 8];
        const size_t frag = ((size_t)head * (n >> 5) + (m0 >> 5)) * 4 + f;
        *(bf16x8*)&hbB[frag * 512 + lane * 8] = v;
    }
}

// ============ aggregate: out_split[s][i][h*64+d] = sum_j P[i,j,h] h[j,h,d] ============
// Barrier-free, LDS-free (R6 proven structure) + two latency fixes for the measured
// 27-us VMEM stall (R6: VGPR_Count 60 -> compiler collapsed the double buffer):
//  - i-tile 64 (mt=4): per-step compute ~2x (covers L3 latency), total loads halved.
//  - prefetch DISTANCE 2: ldks(s+2) issued AFTER consuming buf s&1 -> loads in
//    flight across two full step bodies (~1000 cyc); (256,2) bounds give the
//    allocator a 256-VGPR budget so both buffers can stay live.
__global__ __launch_bounds__(256, 2) void aggregate(
    const unsigned int* __restrict__ adjP32, const float2* __restrict__ Es,
    const float2* __restrict__ Ed, const __hip_bfloat16* __restrict__ hbB,
    float* __restrict__ outsp, float* __restrict__ densp, int n, int KR) {

    const int tid = threadIdx.x;
    const int wave = tid >> 6, lane = tid & 63;
    const int q = lane >> 4, l16 = lane & 15, q8 = q * 8;
    const int i0 = blockIdx.x * 64;
    const int K0 = blockIdx.y * KR;

    // src-side exps for this lane's four rows (head = wave)
    floatx2 es12[4];
    #pragma unroll
    for (int mt = 0; mt < 4; ++mt) {
        const float2 e = Es[(size_t)wave * n + i0 + mt * 16 + l16];
        es12[mt][0] = e.x; es12[mt][1] = e.y;
    }

    // ones-column B-frag for MFMA-based denominator
    union { short s[8]; bf16x8 v; } bones;
    #pragma unroll
    for (int p = 0; p < 8; ++p) bones.s[p] = (l16 == 0) ? (short)0x3F80 : (short)0;

    floatx4 acc[4][4];
    floatx4 accd[4];
    #pragma unroll
    for (int mt = 0; mt < 4; ++mt) {
        accd[mt] = (floatx4){0.f, 0.f, 0.f, 0.f};
        #pragma unroll
        for (int nt = 0; nt < 4; ++nt) acc[mt][nt] = (floatx4){0.f, 0.f, 0.f, 0.f};
    }

    // per-lane row mask pointers (rows i0+mt*16+l16; lanes with same l16 broadcast)
    const unsigned int* aR0 = adjP32 + (size_t)(i0 +      l16) * (n >> 5);
    const unsigned int* aR1 = adjP32 + (size_t)(i0 + 16 + l16) * (n >> 5);
    const unsigned int* aR2 = adjP32 + (size_t)(i0 + 32 + l16) * (n >> 5);
    const unsigned int* aR3 = adjP32 + (size_t)(i0 + 48 + l16) * (n >> 5);
    const float2* edp = Ed + (size_t)wave * n;
    const __hip_bfloat16* hb = hbB + ((size_t)wave * (n >> 5) * 4) * 512 + lane * 8;

    const int ksBase = K0 >> 5;       // global 32-j step index base
    const int nks = KR >> 5;          // steps per block (16 @ SPLITS=8)
    const int NG = nks >> 2;          // uint4 mask groups

    // 2-buffer register pipeline, statically indexed (all buffer indices compile-time)
    float4 edb[2][4];
    bf16x8 hbb[2][4];
    auto ldks = [&](int s, int b) {
        const float4* ev = (const float4*)(edp + (size_t)s * 32 + q8);
        #pragma unroll
        for (int p = 0; p < 4; ++p) edb[b][p] = ev[p];
        #pragma unroll
        for (int nt = 0; nt < 4; ++nt)
            hbb[b][nt] = *(const bf16x8*)(hb + (size_t)(s * 4 + nt) * 512);
    };

    // prologue: steps 0,1 into bufs 0,1 (nks >= 16 always)
    ldks(ksBase, 0);
    ldks(ksBase + 1, 1);
    uint4 am0 = *(const uint4*)&aR0[ksBase];
    uint4 am1 = *(const uint4*)&aR1[ksBase];
    uint4 am2 = *(const uint4*)&aR2[ksBase];
    uint4 am3 = *(const uint4*)&aR3[ksBase];

    for (int g = 0; g < NG; ++g) {
        const int gn = (g + 1 < NG) ? g + 1 : 0;           // tail clamp: dummy reload
        const uint4 an0 = *(const uint4*)&aR0[ksBase + gn * 4];
        const uint4 an1 = *(const uint4*)&aR1[ksBase + gn * 4];
        const uint4 an2 = *(const uint4*)&aR2[ksBase + gn * 4];
        const uint4 an3 = *(const uint4*)&aR3[ksBase + gn * 4];
        #pragma unroll
        for (int k4 = 0; k4 < 4; ++k4) {
            const int sidx = g * 4 + k4;
            const int cb = sidx & 1;                       // == k4&1 (4 steps/group)
            #pragma unroll
            for (int mt = 0; mt < 4; ++mt) {
                const uint4 amv = mt == 0 ? am0 : mt == 1 ? am1 : mt == 2 ? am2 : am3;
                const unsigned int wmt = k4 == 0 ? amv.x : k4 == 1 ? amv.y
                                       : k4 == 2 ? amv.z : amv.w;
                union { unsigned int u[4]; bf16x8 v; } af;
                #pragma unroll
                for (int p = 0; p < 4; ++p) {
                    const float4 e = edb[cb][p];           // (e^pd,e^.2pd) j=s*32+q8+2p, +1
                    const float wa = fmaxf(es12[mt][0] * e.x, es12[mt][1] * e.y);
                    const float wb = fmaxf(es12[mt][0] * e.z, es12[mt][1] * e.w);
                    const unsigned int sh = wmt >> (q8 + 2 * p);
                    const unsigned int mm = ((sh & 1u) ? 0xFFFFu : 0u) |
                                            ((sh & 2u) ? 0xFFFF0000u : 0u);
                    af.u[p] = __builtin_amdgcn_perm(__float_as_uint(wb), __float_as_uint(wa),
                                                    0x07060302u) & mm;
                }
                #pragma unroll
                for (int nt = 0; nt < 4; ++nt)
                    acc[mt][nt] = __builtin_amdgcn_mfma_f32_16x16x32_bf16(af.v, hbb[cb][nt], acc[mt][nt], 0, 0, 0);
                accd[mt] = __builtin_amdgcn_mfma_f32_16x16x32_bf16(af.v, bones.v, accd[mt], 0, 0, 0);
            }
            // prefetch step sidx+2 into the buffer just consumed (distance-2 pipeline)
            const int sn2 = (sidx + 2 < nks) ? ksBase + sidx + 2 : ksBase;
            ldks(sn2, cb);
        }
        am0 = an0; am1 = an1; am2 = an2; am3 = an3;
    }

    // ---- epilogue: disjoint per-split writes, no atomics ----
    const size_t sOut = (size_t)blockIdx.y * n * HD;
    #pragma unroll
    for (int mt = 0; mt < 4; ++mt)
        #pragma unroll
        for (int nt = 0; nt < 4; ++nt)
            #pragma unroll
            for (int r = 0; r < 4; ++r)
                outsp[sOut + (size_t)(i0 + mt * 16 + q * 4 + r) * HD + wave * ODIM + nt * 16 + l16] = acc[mt][nt][r];
    if (l16 == 0) {
        #pragma unroll
        for (int mt = 0; mt < 4; ++mt)
            #pragma unroll
            for (int r = 0; r < 4; ++r)
                densp[((size_t)blockIdx.y * n + i0 + mt * 16 + q * 4 + r) * HEADS + wave] = accd[mt][r];
    }
}

// ============ normalize: out = sum_s outsp / sum_s densp ============
__global__ __launch_bounds__(256) void normalize(const float* __restrict__ outsp,
                                                 const float* __restrict__ densp,
                                                 float* __restrict__ out, int n, int splits) {
    const int g = blockIdx.x * 256 + threadIdx.x;
    const int i = g >> 6;
    const int c4 = (g & 63) * 4;
    const int head = c4 >> 6;
    float den = 0.f;
    for (int s = 0; s < splits; ++s) den += densp[((size_t)s * n + i) * HEADS + head];
    float4 v = {0.f, 0.f, 0.f, 0.f};
    for (int s = 0; s < splits; ++s) {
        const float4 t = *(const float4*)&outsp[(size_t)s * n * HD + (size_t)i * HD + c4];
        v.x += t.x; v.y += t.y; v.z += t.z; v.w += t.w;
    }
    const float inv = 1.0f / den;
    v.x *= inv; v.y *= inv; v.z *= inv; v.w *= inv;
    *(float4*)&out[(size_t)i * HD + c4] = v;
}

extern "C" void kernel_launch(void* const* d_in, const int* in_sizes, int n_in,
                              void* d_out, int out_size, void* d_ws, size_t ws_size,
                              hipStream_t stream) {
    const float* x   = (const float*)d_in[0];
    const int*   adj = (const int*)d_in[1];
    const float* W   = (const float*)d_in[2];
    const float* att = (const float*)d_in[3];
    float* out = (float*)d_out;

    const int in_dim = in_sizes[2] / HD;   // 256
    const int n = in_sizes[0] / in_dim;    // 4096

    char* ws = (char*)d_ws;
    size_t off = 0;
    auto alloc = [&](size_t bytes) -> void* {
        void* p = ws + off; off += (bytes + 255) & ~(size_t)255; return p;
    };
    __hip_bfloat16* xh = (__hip_bfloat16*)alloc((size_t)n * in_dim * 2);
    __hip_bfloat16* xl = (__hip_bfloat16*)alloc((size_t)n * in_dim * 2);
    __hip_bfloat16* wh = (__hip_bfloat16*)alloc((size_t)in_dim * HD * 2);
    __hip_bfloat16* wl = (__hip_bfloat16*)alloc((size_t)in_dim * HD * 2);
    float2*         Es = (float2*)alloc((size_t)HEADS * n * 8);
    float2*         Ed = (float2*)alloc((size_t)HEADS * n * 8);
    __hip_bfloat16* hbB = (__hip_bfloat16*)alloc((size_t)n * HD * 2);
    unsigned long long* adjP = (unsigned long long*)alloc((size_t)n * (n >> 6) * 8);

    const size_t outB = (size_t)n * HD * 4, denB = (size_t)n * HEADS * 4;
    // SPLITS=8 (512 blocks at i-tile 64) when workspace allows; fallback 4.
    int splits = SPLITS;
    if (ws_size && off + (size_t)splits * (((outB + 255) & ~(size_t)255) + ((denB + 255) & ~(size_t)255)) > ws_size)
        splits = 4;
    float* densp = (float*)alloc((size_t)splits * denB);
    float* outsp = (float*)alloc((size_t)splits * outB);

    const int nxb = (n / 16) * (in_dim / 32) * 64 / 256;
    const int nwb = (HD / 16) * (in_dim / 32) * 64 / 256;
    pack_xw<<<nxb + nwb, 256, 0, stream>>>(x, W, xh, xl, wh, wl, in_dim, nxb);
    gemm_fused<<<dim3(n / 32, HEADS + 2), 128, 0, stream>>>(xh, xl, wh, wl, att, adj,
                                                            Es, Ed, hbB, adjP, n, in_dim);
    aggregate<<<dim3(n / 64, splits), 256, 0, stream>>>((const unsigned int*)adjP, Es, Ed,
                                                        hbB, outsp, densp, n, n / splits);
    normalize<<<n * 64 / 256, 256, 0, stream>>>(outsp, densp, out, n, splits);
}

// Round 8
// 155.291 us; speedup vs baseline: 1.0758x; 1.0670x over previous
//
#include <hip/hip_runtime.h>
#include <hip/hip_bf16.h>

#define HEADS 4
#define ODIM 64
#define HD 256          // HEADS*ODIM
#define NEG_SLOPE 0.2f
#define SPLITS 8

typedef __attribute__((ext_vector_type(8))) short bf16x8;
typedef __attribute__((ext_vector_type(4))) float floatx4;
typedef __attribute__((ext_vector_type(2))) float floatx2;

// ============ pack x and W -> bf16 hi/lo MFMA fragments (x/W only) ============
// A-frag layout: frag[(mc*Kc + kc)][lane][8], lane=(l16,q): A[m=mc*16+l16][k=kc*32+q*8+p]
// B-frag layout: frag[(nc*Kc + kc)][lane][8], lane=(l16,q): B[k=kc*32+q*8+p][n=nc*16+l16]
__global__ __launch_bounds__(256) void pack_xw(const float* __restrict__ x,
                                               const float* __restrict__ W,
                                               __hip_bfloat16* __restrict__ xh,
                                               __hip_bfloat16* __restrict__ xl,
                                               __hip_bfloat16* __restrict__ wh,
                                               __hip_bfloat16* __restrict__ wl,
                                               int K, int nxb) {
    const int b = blockIdx.x;
    const int Kc = K >> 5;
    if (b < nxb) {
        const int g = b * 256 + threadIdx.x;
        const int lane = g & 63, frag = g >> 6;
        const int kc = frag % Kc, mc = frag / Kc;
        const int l16 = lane & 15, q = lane >> 4;
        const float* src = x + (size_t)(mc * 16 + l16) * K + kc * 32 + q * 8;
        const float4 v0 = *(const float4*)src;
        const float4 v1 = *(const float4*)(src + 4);
        const float vv[8] = {v0.x, v0.y, v0.z, v0.w, v1.x, v1.y, v1.z, v1.w};
        union { __hip_bfloat16 b[8]; bf16x8 v; } H, L;
        #pragma unroll
        for (int p = 0; p < 8; ++p) {
            H.b[p] = __float2bfloat16(vv[p]);
            L.b[p] = __float2bfloat16(vv[p] - __bfloat162float(H.b[p]));
        }
        *(bf16x8*)&xh[(size_t)frag * 512 + lane * 8] = H.v;
        *(bf16x8*)&xl[(size_t)frag * 512 + lane * 8] = L.v;
    } else {
        const int g = (b - nxb) * 256 + threadIdx.x;
        const int lane = g & 63, frag = g >> 6;
        const int kc = frag % Kc, nc = frag / Kc;
        const int l16 = lane & 15, q = lane >> 4;
        union { __hip_bfloat16 b[8]; bf16x8 v; } H, L;
        #pragma unroll
        for (int p = 0; p < 8; ++p) {
            const float w = W[(size_t)(kc * 32 + q * 8 + p) * HD + nc * 16 + l16];
            H.b[p] = __float2bfloat16(w);
            L.b[p] = __float2bfloat16(w - __bfloat162float(H.b[p]));
        }
        *(bf16x8*)&wh[(size_t)frag * 512 + lane * 8] = H.v;
        *(bf16x8*)&wl[(size_t)frag * 512 + lane * 8] = L.v;
    }
}

// ============ adj bit-pack: STANDALONE, sized for BW (R7 lesson: fused into gemm it
// got a 32-VGPR allocation + 2 waves/CU straggler tail = 41-51 us kernel).
// 1024 blocks x 4 waves = 4096 waves, 4 row-quarter tasks each; all 16 seg-loads
// issued before any ballot -> 16 MB in flight device-wide >> 2.4 MB needed for
// 900-cyc HBM latency -> true BW-bound: 64 MB / ~6 TB/s ~ 12 us.
// adjP layout: bit (j&63) of adjP[i*(n/64) + (j>>6)] = (adj[i][j] > 0)
__global__ __launch_bounds__(256) void adj_pack(const int* __restrict__ adj,
                                                unsigned long long* __restrict__ adjP,
                                                int n) {
    const int wv = threadIdx.x >> 6, ln = threadIdx.x & 63;
    const int gw = blockIdx.x * 4 + wv;
    const int nw = gridDim.x * 4;
    const int segs = n >> 6;
    for (int t = gw; t < n * 4; t += nw) {
        const int row = t >> 2, qq = t & 3;
        const int* ar = adj + (size_t)row * n + (size_t)qq * 1024;
        unsigned long long* dst = adjP + (size_t)row * segs + qq * 16;
        int v[16];
        #pragma unroll
        for (int s = 0; s < 16; ++s) v[s] = ar[s * 64 + ln];
        #pragma unroll
        for (int s = 0; s < 16; ++s) {
            const unsigned long long m = __ballot(v[s] > 0);
            if (ln == 0) dst[s] = m;
        }
    }
}

// ============ fused GEMM: h = x@W (hi/lo bf16 MFMA) + E epilogue + B-frag pack of h ============
// Reverted to the pure form (no adj branch): block 128 (2 waves, 16 rows each),
// grid (n/32, HEADS) = 512 blocks (2/CU). Proven ~10 us in R0-R5 profiles.
// E output per-head: Es[h*n+i] = (e^ps, e^.2ps), Ed[h*n+i] = (e^pd, e^.2pd).
__global__ __launch_bounds__(128) void gemm_fused(
    const __hip_bfloat16* __restrict__ xh, const __hip_bfloat16* __restrict__ xl,
    const __hip_bfloat16* __restrict__ wh, const __hip_bfloat16* __restrict__ wl,
    const float* __restrict__ att, float2* __restrict__ Es, float2* __restrict__ Ed,
    __hip_bfloat16* __restrict__ hbB, int n, int K) {

    __shared__ __hip_bfloat16 T[64][40];   // h^T tile [d][j(32)], stride 40 (16B-aligned rows)

    const int tid = threadIdx.x, wave = tid >> 6, lane = tid & 63;
    const int q = lane >> 4, l16 = lane & 15;
    const int m0 = blockIdx.x * 32;
    const int head = blockIdx.y;
    const int Kc = K >> 5;
    const int mc = (m0 >> 4) + wave;

    floatx4 acc[4] = {{0.f,0.f,0.f,0.f},{0.f,0.f,0.f,0.f},{0.f,0.f,0.f,0.f},{0.f,0.f,0.f,0.f}};

    const __hip_bfloat16* Axh = xh + (size_t)mc * Kc * 512 + lane * 8;
    const __hip_bfloat16* Axl = xl + (size_t)mc * Kc * 512 + lane * 8;
    const __hip_bfloat16* Bwh = wh + lane * 8;
    const __hip_bfloat16* Bwl = wl + lane * 8;
    #pragma unroll 2
    for (int kc = 0; kc < Kc; ++kc) {
        const bf16x8 ah = *(const bf16x8*)(Axh + (size_t)kc * 512);
        const bf16x8 al = *(const bf16x8*)(Axl + (size_t)kc * 512);
        bf16x8 bh[4], bl[4];
        #pragma unroll
        for (int nt = 0; nt < 4; ++nt) {
            const size_t fo = (size_t)((head * 4 + nt) * Kc + kc) * 512;
            bh[nt] = *(const bf16x8*)(Bwh + fo);
            bl[nt] = *(const bf16x8*)(Bwl + fo);
        }
        // pass-major order: dependency distance 4 between same-acc MFMAs
        #pragma unroll
        for (int nt = 0; nt < 4; ++nt)
            acc[nt] = __builtin_amdgcn_mfma_f32_16x16x32_bf16(ah, bh[nt], acc[nt], 0, 0, 0);
        #pragma unroll
        for (int nt = 0; nt < 4; ++nt)
            acc[nt] = __builtin_amdgcn_mfma_f32_16x16x32_bf16(ah, bl[nt], acc[nt], 0, 0, 0);
        #pragma unroll
        for (int nt = 0; nt < 4; ++nt)
            acc[nt] = __builtin_amdgcn_mfma_f32_16x16x32_bf16(al, bh[nt], acc[nt], 0, 0, 0);
    }

    // ---- E epilogue: e_src/e_dst row sums via shuffle over the 16-lane group ----
    float as_v[4], ad_v[4];
    #pragma unroll
    for (int nt = 0; nt < 4; ++nt) {
        as_v[nt] = att[head * 2 * ODIM + nt * 16 + l16];
        ad_v[nt] = att[head * 2 * ODIM + ODIM + nt * 16 + l16];
    }
    #pragma unroll
    for (int r = 0; r < 4; ++r) {
        float ps = 0.f, pd = 0.f;
        #pragma unroll
        for (int nt = 0; nt < 4; ++nt) {
            ps = fmaf(acc[nt][r], as_v[nt], ps);
            pd = fmaf(acc[nt][r], ad_v[nt], pd);
        }
        #pragma unroll
        for (int m = 1; m <= 8; m <<= 1) {
            ps += __shfl_xor(ps, m, 64);
            pd += __shfl_xor(pd, m, 64);
        }
        if (l16 == 0) {
            const int i = m0 + wave * 16 + q * 4 + r;
            Es[head * n + i] = make_float2(__expf(ps), __expf(NEG_SLOPE * ps));
            Ed[head * n + i] = make_float2(__expf(pd), __expf(NEG_SLOPE * pd));
        }
    }

    // ---- write h tile transposed to LDS as bf16 ----
    #pragma unroll
    for (int nt = 0; nt < 4; ++nt) {
        union { __hip_bfloat16 b[4]; uint2 u; } pk;
        #pragma unroll
        for (int r = 0; r < 4; ++r) pk.b[r] = __float2bfloat16(acc[nt][r]);
        *(uint2*)&T[nt * 16 + l16][wave * 16 + q * 4] = pk.u;
    }
    __syncthreads();

    // ---- emit packed B-frags of h: frag[(head*(n/32) + j32)*4 + nt][lane][8] ----
    #pragma unroll
    for (int ffi = 0; ffi < 2; ++ffi) {
        const int f = wave + ffi * 2;   // nt
        const bf16x8 v = *(const bf16x8*)&T[f * 16 + l16][q * 8];
        const size_t frag = ((size_t)head * (n >> 5) + (m0 >> 5)) * 4 + f;
        *(bf16x8*)&hbB[frag * 512 + lane * 8] = v;
    }
}

// ============ aggregate: out_split[s][i][h*64+d] = sum_j P[i,j,h] h[j,h,d] ============
// Barrier-free, LDS-free; i-tile 64 (mt=4), distance-2 register prefetch, (256,2)
// bounds for a 256-VGPR budget (R7 structure, UNCHANGED this round so its counters
// are finally attributable in the top-5 profile).
__global__ __launch_bounds__(256, 2) void aggregate(
    const unsigned int* __restrict__ adjP32, const float2* __restrict__ Es,
    const float2* __restrict__ Ed, const __hip_bfloat16* __restrict__ hbB,
    float* __restrict__ outsp, float* __restrict__ densp, int n, int KR) {

    const int tid = threadIdx.x;
    const int wave = tid >> 6, lane = tid & 63;
    const int q = lane >> 4, l16 = lane & 15, q8 = q * 8;
    const int i0 = blockIdx.x * 64;
    const int K0 = blockIdx.y * KR;

    // src-side exps for this lane's four rows (head = wave)
    floatx2 es12[4];
    #pragma unroll
    for (int mt = 0; mt < 4; ++mt) {
        const float2 e = Es[(size_t)wave * n + i0 + mt * 16 + l16];
        es12[mt][0] = e.x; es12[mt][1] = e.y;
    }

    // ones-column B-frag for MFMA-based denominator
    union { short s[8]; bf16x8 v; } bones;
    #pragma unroll
    for (int p = 0; p < 8; ++p) bones.s[p] = (l16 == 0) ? (short)0x3F80 : (short)0;

    floatx4 acc[4][4];
    floatx4 accd[4];
    #pragma unroll
    for (int mt = 0; mt < 4; ++mt) {
        accd[mt] = (floatx4){0.f, 0.f, 0.f, 0.f};
        #pragma unroll
        for (int nt = 0; nt < 4; ++nt) acc[mt][nt] = (floatx4){0.f, 0.f, 0.f, 0.f};
    }

    // per-lane row mask pointers (rows i0+mt*16+l16; lanes with same l16 broadcast)
    const unsigned int* aR0 = adjP32 + (size_t)(i0 +      l16) * (n >> 5);
    const unsigned int* aR1 = adjP32 + (size_t)(i0 + 16 + l16) * (n >> 5);
    const unsigned int* aR2 = adjP32 + (size_t)(i0 + 32 + l16) * (n >> 5);
    const unsigned int* aR3 = adjP32 + (size_t)(i0 + 48 + l16) * (n >> 5);
    const float2* edp = Ed + (size_t)wave * n;
    const __hip_bfloat16* hb = hbB + ((size_t)wave * (n >> 5) * 4) * 512 + lane * 8;

    const int ksBase = K0 >> 5;       // global 32-j step index base
    const int nks = KR >> 5;          // steps per block (16 @ SPLITS=8)
    const int NG = nks >> 2;          // uint4 mask groups

    // 2-buffer register pipeline, statically indexed (all buffer indices compile-time)
    float4 edb[2][4];
    bf16x8 hbb[2][4];
    auto ldks = [&](int s, int b) {
        const float4* ev = (const float4*)(edp + (size_t)s * 32 + q8);
        #pragma unroll
        for (int p = 0; p < 4; ++p) edb[b][p] = ev[p];
        #pragma unroll
        for (int nt = 0; nt < 4; ++nt)
            hbb[b][nt] = *(const bf16x8*)(hb + (size_t)(s * 4 + nt) * 512);
    };

    // prologue: steps 0,1 into bufs 0,1 (nks >= 16 always)
    ldks(ksBase, 0);
    ldks(ksBase + 1, 1);
    uint4 am0 = *(const uint4*)&aR0[ksBase];
    uint4 am1 = *(const uint4*)&aR1[ksBase];
    uint4 am2 = *(const uint4*)&aR2[ksBase];
    uint4 am3 = *(const uint4*)&aR3[ksBase];

    for (int g = 0; g < NG; ++g) {
        const int gn = (g + 1 < NG) ? g + 1 : 0;           // tail clamp: dummy reload
        const uint4 an0 = *(const uint4*)&aR0[ksBase + gn * 4];
        const uint4 an1 = *(const uint4*)&aR1[ksBase + gn * 4];
        const uint4 an2 = *(const uint4*)&aR2[ksBase + gn * 4];
        const uint4 an3 = *(const uint4*)&aR3[ksBase + gn * 4];
        #pragma unroll
        for (int k4 = 0; k4 < 4; ++k4) {
            const int sidx = g * 4 + k4;
            const int cb = sidx & 1;                       // == k4&1 (4 steps/group)
            #pragma unroll
            for (int mt = 0; mt < 4; ++mt) {
                const uint4 amv = mt == 0 ? am0 : mt == 1 ? am1 : mt == 2 ? am2 : am3;
                const unsigned int wmt = k4 == 0 ? amv.x : k4 == 1 ? amv.y
                                       : k4 == 2 ? amv.z : amv.w;
                union { unsigned int u[4]; bf16x8 v; } af;
                #pragma unroll
                for (int p = 0; p < 4; ++p) {
                    const float4 e = edb[cb][p];           // (e^pd,e^.2pd) j=s*32+q8+2p, +1
                    const float wa = fmaxf(es12[mt][0] * e.x, es12[mt][1] * e.y);
                    const float wb = fmaxf(es12[mt][0] * e.z, es12[mt][1] * e.w);
                    const unsigned int sh = wmt >> (q8 + 2 * p);
                    const unsigned int mm = ((sh & 1u) ? 0xFFFFu : 0u) |
                                            ((sh & 2u) ? 0xFFFF0000u : 0u);
                    af.u[p] = __builtin_amdgcn_perm(__float_as_uint(wb), __float_as_uint(wa),
                                                    0x07060302u) & mm;
                }
                #pragma unroll
                for (int nt = 0; nt < 4; ++nt)
                    acc[mt][nt] = __builtin_amdgcn_mfma_f32_16x16x32_bf16(af.v, hbb[cb][nt], acc[mt][nt], 0, 0, 0);
                accd[mt] = __builtin_amdgcn_mfma_f32_16x16x32_bf16(af.v, bones.v, accd[mt], 0, 0, 0);
            }
            // prefetch step sidx+2 into the buffer just consumed (distance-2 pipeline)
            const int sn2 = (sidx + 2 < nks) ? ksBase + sidx + 2 : ksBase;
            ldks(sn2, cb);
        }
        am0 = an0; am1 = an1; am2 = an2; am3 = an3;
    }

    // ---- epilogue: disjoint per-split writes, no atomics ----
    const size_t sOut = (size_t)blockIdx.y * n * HD;
    #pragma unroll
    for (int mt = 0; mt < 4; ++mt)
        #pragma unroll
        for (int nt = 0; nt < 4; ++nt)
            #pragma unroll
            for (int r = 0; r < 4; ++r)
                outsp[sOut + (size_t)(i0 + mt * 16 + q * 4 + r) * HD + wave * ODIM + nt * 16 + l16] = acc[mt][nt][r];
    if (l16 == 0) {
        #pragma unroll
        for (int mt = 0; mt < 4; ++mt)
            #pragma unroll
            for (int r = 0; r < 4; ++r)
                densp[((size_t)blockIdx.y * n + i0 + mt * 16 + q * 4 + r) * HEADS + wave] = accd[mt][r];
    }
}

// ============ normalize: out = sum_s outsp / sum_s densp ============
__global__ __launch_bounds__(256) void normalize(const float* __restrict__ outsp,
                                                 const float* __restrict__ densp,
                                                 float* __restrict__ out, int n, int splits) {
    const int g = blockIdx.x * 256 + threadIdx.x;
    const int i = g >> 6;
    const int c4 = (g & 63) * 4;
    const int head = c4 >> 6;
    float den = 0.f;
    for (int s = 0; s < splits; ++s) den += densp[((size_t)s * n + i) * HEADS + head];
    float4 v = {0.f, 0.f, 0.f, 0.f};
    for (int s = 0; s < splits; ++s) {
        const float4 t = *(const float4*)&outsp[(size_t)s * n * HD + (size_t)i * HD + c4];
        v.x += t.x; v.y += t.y; v.z += t.z; v.w += t.w;
    }
    const float inv = 1.0f / den;
    v.x *= inv; v.y *= inv; v.z *= inv; v.w *= inv;
    *(float4*)&out[(size_t)i * HD + c4] = v;
}

extern "C" void kernel_launch(void* const* d_in, const int* in_sizes, int n_in,
                              void* d_out, int out_size, void* d_ws, size_t ws_size,
                              hipStream_t stream) {
    const float* x   = (const float*)d_in[0];
    const int*   adj = (const int*)d_in[1];
    const float* W   = (const float*)d_in[2];
    const float* att = (const float*)d_in[3];
    float* out = (float*)d_out;

    const int in_dim = in_sizes[2] / HD;   // 256
    const int n = in_sizes[0] / in_dim;    // 4096

    char* ws = (char*)d_ws;
    size_t off = 0;
    auto alloc = [&](size_t bytes) -> void* {
        void* p = ws + off; off += (bytes + 255) & ~(size_t)255; return p;
    };
    __hip_bfloat16* xh = (__hip_bfloat16*)alloc((size_t)n * in_dim * 2);
    __hip_bfloat16* xl = (__hip_bfloat16*)alloc((size_t)n * in_dim * 2);
    __hip_bfloat16* wh = (__hip_bfloat16*)alloc((size_t)in_dim * HD * 2);
    __hip_bfloat16* wl = (__hip_bfloat16*)alloc((size_t)in_dim * HD * 2);
    float2*         Es = (float2*)alloc((size_t)HEADS * n * 8);
    float2*         Ed = (float2*)alloc((size_t)HEADS * n * 8);
    __hip_bfloat16* hbB = (__hip_bfloat16*)alloc((size_t)n * HD * 2);
    unsigned long long* adjP = (unsigned long long*)alloc((size_t)n * (n >> 6) * 8);

    const size_t outB = (size_t)n * HD * 4, denB = (size_t)n * HEADS * 4;
    // SPLITS=8 (512 blocks at i-tile 64) when workspace allows; fallback 4.
    int splits = SPLITS;
    if (ws_size && off + (size_t)splits * (((outB + 255) & ~(size_t)255) + ((denB + 255) & ~(size_t)255)) > ws_size)
        splits = 4;
    float* densp = (float*)alloc((size_t)splits * denB);
    float* outsp = (float*)alloc((size_t)splits * outB);

    const int nxb = (n / 16) * (in_dim / 32) * 64 / 256;
    const int nwb = (HD / 16) * (in_dim / 32) * 64 / 256;
    pack_xw<<<nxb + nwb, 256, 0, stream>>>(x, W, xh, xl, wh, wl, in_dim, nxb);
    adj_pack<<<1024, 256, 0, stream>>>(adj, adjP, n);
    gemm_fused<<<dim3(n / 32, HEADS), 128, 0, stream>>>(xh, xl, wh, wl, att, Es, Ed, hbB, n, in_dim);
    aggregate<<<dim3(n / 64, splits), 256, 0, stream>>>((const unsigned int*)adjP, Es, Ed,
                                                        hbB, outsp, densp, n, n / splits);
    normalize<<<n * 64 / 256, 256, 0, stream>>>(outsp, densp, out, n, splits);
}

// Round 9
// 153.886 us; speedup vs baseline: 1.0856x; 1.0091x over previous
//
#include <hip/hip_runtime.h>
#include <hip/hip_bf16.h>

#define HEADS 4
#define ODIM 64
#define HD 256          // HEADS*ODIM
#define NEG_SLOPE 0.2f
#define SPLITS 8

typedef __attribute__((ext_vector_type(8))) short bf16x8;
typedef __attribute__((ext_vector_type(4))) float floatx4;
typedef __attribute__((ext_vector_type(2))) float floatx2;

// async global->LDS DMA, 16B/lane, dest = wave-uniform base + lane*16 (no VGPR dest:
// the compiler CANNOT collapse this pipeline into serial load->drain->use chains,
// which is what it did to every register-based prefetch attempt R4-R8, VGPR_Count=60).
#define GLL(g, l) __builtin_amdgcn_global_load_lds( \
    (const __attribute__((address_space(1))) unsigned int*)(const void*)(g), \
    (__attribute__((address_space(3))) unsigned int*)(void*)(l), 16, 0, 0)

// ============ pack x and W -> bf16 hi/lo MFMA fragments (x/W only) ============
// A-frag layout: frag[(mc*Kc + kc)][lane][8], lane=(l16,q): A[m=mc*16+l16][k=kc*32+q*8+p]
// B-frag layout: frag[(nc*Kc + kc)][lane][8], lane=(l16,q): B[k=kc*32+q*8+p][n=nc*16+l16]
__global__ __launch_bounds__(256) void pack_xw(const float* __restrict__ x,
                                               const float* __restrict__ W,
                                               __hip_bfloat16* __restrict__ xh,
                                               __hip_bfloat16* __restrict__ xl,
                                               __hip_bfloat16* __restrict__ wh,
                                               __hip_bfloat16* __restrict__ wl,
                                               int K, int nxb) {
    const int b = blockIdx.x;
    const int Kc = K >> 5;
    if (b < nxb) {
        const int g = b * 256 + threadIdx.x;
        const int lane = g & 63, frag = g >> 6;
        const int kc = frag % Kc, mc = frag / Kc;
        const int l16 = lane & 15, q = lane >> 4;
        const float* src = x + (size_t)(mc * 16 + l16) * K + kc * 32 + q * 8;
        const float4 v0 = *(const float4*)src;
        const float4 v1 = *(const float4*)(src + 4);
        const float vv[8] = {v0.x, v0.y, v0.z, v0.w, v1.x, v1.y, v1.z, v1.w};
        union { __hip_bfloat16 b[8]; bf16x8 v; } H, L;
        #pragma unroll
        for (int p = 0; p < 8; ++p) {
            H.b[p] = __float2bfloat16(vv[p]);
            L.b[p] = __float2bfloat16(vv[p] - __bfloat162float(H.b[p]));
        }
        *(bf16x8*)&xh[(size_t)frag * 512 + lane * 8] = H.v;
        *(bf16x8*)&xl[(size_t)frag * 512 + lane * 8] = L.v;
    } else {
        const int g = (b - nxb) * 256 + threadIdx.x;
        const int lane = g & 63, frag = g >> 6;
        const int kc = frag % Kc, nc = frag / Kc;
        const int l16 = lane & 15, q = lane >> 4;
        union { __hip_bfloat16 b[8]; bf16x8 v; } H, L;
        #pragma unroll
        for (int p = 0; p < 8; ++p) {
            const float w = W[(size_t)(kc * 32 + q * 8 + p) * HD + nc * 16 + l16];
            H.b[p] = __float2bfloat16(w);
            L.b[p] = __float2bfloat16(w - __bfloat162float(H.b[p]));
        }
        *(bf16x8*)&wh[(size_t)frag * 512 + lane * 8] = H.v;
        *(bf16x8*)&wl[(size_t)frag * 512 + lane * 8] = L.v;
    }
}

// ============ adj bit-pack: standalone, BW-sized (R8 proven) ============
// adjP layout: bit (j&63) of adjP[i*(n/64) + (j>>6)] = (adj[i][j] > 0)
__global__ __launch_bounds__(256) void adj_pack(const int* __restrict__ adj,
                                                unsigned long long* __restrict__ adjP,
                                                int n) {
    const int wv = threadIdx.x >> 6, ln = threadIdx.x & 63;
    const int gw = blockIdx.x * 4 + wv;
    const int nw = gridDim.x * 4;
    const int segs = n >> 6;
    for (int t = gw; t < n * 4; t += nw) {
        const int row = t >> 2, qq = t & 3;
        const int* ar = adj + (size_t)row * n + (size_t)qq * 1024;
        unsigned long long* dst = adjP + (size_t)row * segs + qq * 16;
        int v[16];
        #pragma unroll
        for (int s = 0; s < 16; ++s) v[s] = ar[s * 64 + ln];
        #pragma unroll
        for (int s = 0; s < 16; ++s) {
            const unsigned long long m = __ballot(v[s] > 0);
            if (ln == 0) dst[s] = m;
        }
    }
}

// ============ fused GEMM: h = x@W (hi/lo bf16 MFMA) + E epilogue + B-frag pack of h ============
// block 128 (2 waves, 16 rows each), grid (n/32, HEADS) = 512 blocks. Proven form.
__global__ __launch_bounds__(128) void gemm_fused(
    const __hip_bfloat16* __restrict__ xh, const __hip_bfloat16* __restrict__ xl,
    const __hip_bfloat16* __restrict__ wh, const __hip_bfloat16* __restrict__ wl,
    const float* __restrict__ att, float2* __restrict__ Es, float2* __restrict__ Ed,
    __hip_bfloat16* __restrict__ hbB, int n, int K) {

    __shared__ __hip_bfloat16 T[64][40];   // h^T tile [d][j(32)], stride 40 (16B-aligned rows)

    const int tid = threadIdx.x, wave = tid >> 6, lane = tid & 63;
    const int q = lane >> 4, l16 = lane & 15;
    const int m0 = blockIdx.x * 32;
    const int head = blockIdx.y;
    const int Kc = K >> 5;
    const int mc = (m0 >> 4) + wave;

    floatx4 acc[4] = {{0.f,0.f,0.f,0.f},{0.f,0.f,0.f,0.f},{0.f,0.f,0.f,0.f},{0.f,0.f,0.f,0.f}};

    const __hip_bfloat16* Axh = xh + (size_t)mc * Kc * 512 + lane * 8;
    const __hip_bfloat16* Axl = xl + (size_t)mc * Kc * 512 + lane * 8;
    const __hip_bfloat16* Bwh = wh + lane * 8;
    const __hip_bfloat16* Bwl = wl + lane * 8;
    #pragma unroll 2
    for (int kc = 0; kc < Kc; ++kc) {
        const bf16x8 ah = *(const bf16x8*)(Axh + (size_t)kc * 512);
        const bf16x8 al = *(const bf16x8*)(Axl + (size_t)kc * 512);
        bf16x8 bh[4], bl[4];
        #pragma unroll
        for (int nt = 0; nt < 4; ++nt) {
            const size_t fo = (size_t)((head * 4 + nt) * Kc + kc) * 512;
            bh[nt] = *(const bf16x8*)(Bwh + fo);
            bl[nt] = *(const bf16x8*)(Bwl + fo);
        }
        // pass-major order: dependency distance 4 between same-acc MFMAs
        #pragma unroll
        for (int nt = 0; nt < 4; ++nt)
            acc[nt] = __builtin_amdgcn_mfma_f32_16x16x32_bf16(ah, bh[nt], acc[nt], 0, 0, 0);
        #pragma unroll
        for (int nt = 0; nt < 4; ++nt)
            acc[nt] = __builtin_amdgcn_mfma_f32_16x16x32_bf16(ah, bl[nt], acc[nt], 0, 0, 0);
        #pragma unroll
        for (int nt = 0; nt < 4; ++nt)
            acc[nt] = __builtin_amdgcn_mfma_f32_16x16x32_bf16(al, bh[nt], acc[nt], 0, 0, 0);
    }

    // ---- E epilogue: e_src/e_dst row sums via shuffle over the 16-lane group ----
    float as_v[4], ad_v[4];
    #pragma unroll
    for (int nt = 0; nt < 4; ++nt) {
        as_v[nt] = att[head * 2 * ODIM + nt * 16 + l16];
        ad_v[nt] = att[head * 2 * ODIM + ODIM + nt * 16 + l16];
    }
    #pragma unroll
    for (int r = 0; r < 4; ++r) {
        float ps = 0.f, pd = 0.f;
        #pragma unroll
        for (int nt = 0; nt < 4; ++nt) {
            ps = fmaf(acc[nt][r], as_v[nt], ps);
            pd = fmaf(acc[nt][r], ad_v[nt], pd);
        }
        #pragma unroll
        for (int m = 1; m <= 8; m <<= 1) {
            ps += __shfl_xor(ps, m, 64);
            pd += __shfl_xor(pd, m, 64);
        }
        if (l16 == 0) {
            const int i = m0 + wave * 16 + q * 4 + r;
            Es[head * n + i] = make_float2(__expf(ps), __expf(NEG_SLOPE * ps));
            Ed[head * n + i] = make_float2(__expf(pd), __expf(NEG_SLOPE * pd));
        }
    }

    // ---- write h tile transposed to LDS as bf16 ----
    #pragma unroll
    for (int nt = 0; nt < 4; ++nt) {
        union { __hip_bfloat16 b[4]; uint2 u; } pk;
        #pragma unroll
        for (int r = 0; r < 4; ++r) pk.b[r] = __float2bfloat16(acc[nt][r]);
        *(uint2*)&T[nt * 16 + l16][wave * 16 + q * 4] = pk.u;
    }
    __syncthreads();

    // ---- emit packed B-frags of h: frag[(head*(n/32) + j32)*4 + nt][lane][8] ----
    #pragma unroll
    for (int ffi = 0; ffi < 2; ++ffi) {
        const int f = wave + ffi * 2;   // nt
        const bf16x8 v = *(const bf16x8*)&T[f * 16 + l16][q * 8];
        const size_t frag = ((size_t)head * (n >> 5) + (m0 >> 5)) * 4 + f;
        *(bf16x8*)&hbB[frag * 512 + lane * 8] = v;
    }
}

// ============ aggregate: out_split[s][i][h*64+d] = sum_j P[i,j,h] h[j,h,d] ============
// T3-minimum 2-phase LDS pipeline via global_load_lds (the compiler-proof form of the
// prefetch that R4-R8's register pipelines failed to keep: hipcc collapsed them to
// serial load->drain->use, VGPR_Count=60, ~8 serialized ~700cyc loads/step = the
// invariant 41 us). Here the staging loads have NO VGPR destination; they stay in
// flight across the whole compute phase; one vmcnt(0) drain per chunk at the barrier.
// chunk = 64 j (2 steps); LDS 68KB (hb dbuf 64K + Ed dbuf 4K) -> 2 blocks/CU.
__global__ __launch_bounds__(256, 2) void aggregate(
    const unsigned int* __restrict__ adjP32, const float2* __restrict__ Es,
    const float2* __restrict__ Ed, const __hip_bfloat16* __restrict__ hbB,
    float* __restrict__ outsp, float* __restrict__ densp, int n, int KR) {

    __shared__ __hip_bfloat16 hbL[2][HEADS][2][4][512];  // [buf][head][step][nt][frag] 64KB
    __shared__ float2 EdL[2][HEADS][64];                  // [buf][head][j]              4KB

    const int tid = threadIdx.x;
    const int wave = tid >> 6, lane = tid & 63;
    const int q = lane >> 4, l16 = lane & 15, q8 = q * 8;
    const int i0 = blockIdx.x * 64;
    const int K0 = blockIdx.y * KR;

    // src-side exps for this lane's four rows (head = wave)
    floatx2 es12[4];
    #pragma unroll
    for (int mt = 0; mt < 4; ++mt) {
        const float2 e = Es[(size_t)wave * n + i0 + mt * 16 + l16];
        es12[mt][0] = e.x; es12[mt][1] = e.y;
    }

    // ones-column B-frag for MFMA-based denominator
    union { short s[8]; bf16x8 v; } bones;
    #pragma unroll
    for (int p = 0; p < 8; ++p) bones.s[p] = (l16 == 0) ? (short)0x3F80 : (short)0;

    floatx4 acc[4][4];
    floatx4 accd[4];
    #pragma unroll
    for (int mt = 0; mt < 4; ++mt) {
        accd[mt] = (floatx4){0.f, 0.f, 0.f, 0.f};
        #pragma unroll
        for (int nt = 0; nt < 4; ++nt) acc[mt][nt] = (floatx4){0.f, 0.f, 0.f, 0.f};
    }

    // per-lane mask row pointers as uint2 (64 bits = one 64-j chunk per row)
    const uint2* aR0 = (const uint2*)(adjP32 + (size_t)(i0 +      l16) * (n >> 5));
    const uint2* aR1 = (const uint2*)(adjP32 + (size_t)(i0 + 16 + l16) * (n >> 5));
    const uint2* aR2 = (const uint2*)(adjP32 + (size_t)(i0 + 32 + l16) * (n >> 5));
    const uint2* aR3 = (const uint2*)(adjP32 + (size_t)(i0 + 48 + l16) * (n >> 5));

    const int ch0 = K0 >> 6;          // global 64-j chunk base
    const int nch = KR >> 6;          // chunks per block (8 @ SPLITS=8)

    // ---- stage chunk cg (global chunk index) into LDS buffer b ----
    auto stage = [&](int b, int cg) {
        const int j32 = cg * 2;       // global 32-j step base
        #pragma unroll
        for (int st = 0; st < 2; ++st)
            #pragma unroll
            for (int nt = 0; nt < 4; ++nt) {
                const size_t frag = ((size_t)wave * (n >> 5) + j32 + st) * 4 + nt;
                GLL(hbB + frag * 512 + lane * 8, &hbL[b][wave][st][nt][0]);
            }
        if (wave < 2) {               // Ed: wave0 -> heads 0,1; wave1 -> heads 2,3
            const int head = wave * 2 + (lane >> 5);
            GLL(Ed + (size_t)head * n + cg * 64 + (lane & 31) * 2, &EdL[b][wave * 2][0]);
        }
    };

    // ---- compute chunk cg from LDS buffer b, masks in registers ----
    auto computeChunk = [&](int b, uint2 m0, uint2 m1, uint2 m2, uint2 m3) {
        #pragma unroll
        for (int st = 0; st < 2; ++st) {
            bf16x8 bc[4];
            #pragma unroll
            for (int nt = 0; nt < 4; ++nt)
                bc[nt] = *(const bf16x8*)&hbL[b][wave][st][nt][lane * 8];
            const float4* ep = (const float4*)&EdL[b][wave][st * 32 + q8];
            const float4 e01 = ep[0], e23 = ep[1], e45 = ep[2], e67 = ep[3];
            #pragma unroll
            for (int mt = 0; mt < 4; ++mt) {
                const uint2 mv = mt == 0 ? m0 : mt == 1 ? m1 : mt == 2 ? m2 : m3;
                const unsigned int wmt = st ? mv.y : mv.x;
                union { unsigned int u[4]; bf16x8 v; } af;
                #pragma unroll
                for (int p = 0; p < 4; ++p) {
                    const float4 e = p == 0 ? e01 : p == 1 ? e23 : p == 2 ? e45 : e67;
                    const float wa = fmaxf(es12[mt][0] * e.x, es12[mt][1] * e.y);
                    const float wb = fmaxf(es12[mt][0] * e.z, es12[mt][1] * e.w);
                    const unsigned int sh = wmt >> (q8 + 2 * p);
                    const unsigned int mm = ((sh & 1u) ? 0xFFFFu : 0u) |
                                            ((sh & 2u) ? 0xFFFF0000u : 0u);
                    af.u[p] = __builtin_amdgcn_perm(__float_as_uint(wb), __float_as_uint(wa),
                                                    0x07060302u) & mm;
                }
                #pragma unroll
                for (int nt = 0; nt < 4; ++nt)
                    acc[mt][nt] = __builtin_amdgcn_mfma_f32_16x16x32_bf16(af.v, bc[nt], acc[mt][nt], 0, 0, 0);
                accd[mt] = __builtin_amdgcn_mfma_f32_16x16x32_bf16(af.v, bones.v, accd[mt], 0, 0, 0);
            }
        }
    };

    // ---- prologue: stage chunk0 -> buf0; masks chunk0 -> regs; drain+barrier ----
    stage(0, ch0);
    uint2 mc0 = aR0[ch0], mc1 = aR1[ch0], mc2 = aR2[ch0], mc3 = aR3[ch0];
    __syncthreads();   // emits s_waitcnt vmcnt(0) + s_barrier

    // ---- main loop: STAGE(next) || prefetch masks || compute(cur) ; barrier ----
    for (int c = 0; c < nch; ++c) {
        if (c + 1 < nch) stage((c & 1) ^ 1, ch0 + c + 1);
        const int cn = (c + 1 < nch) ? ch0 + c + 1 : ch0;   // tail: dummy reload
        const uint2 mn0 = aR0[cn], mn1 = aR1[cn], mn2 = aR2[cn], mn3 = aR3[cn];
        computeChunk(c & 1, mc0, mc1, mc2, mc3);
        __syncthreads();   // drains the in-flight stage loads (they overlapped compute)
        mc0 = mn0; mc1 = mn1; mc2 = mn2; mc3 = mn3;
    }

    // ---- epilogue: disjoint per-split writes, no atomics ----
    const size_t sOut = (size_t)blockIdx.y * n * HD;
    #pragma unroll
    for (int mt = 0; mt < 4; ++mt)
        #pragma unroll
        for (int nt = 0; nt < 4; ++nt)
            #pragma unroll
            for (int r = 0; r < 4; ++r)
                outsp[sOut + (size_t)(i0 + mt * 16 + q * 4 + r) * HD + wave * ODIM + nt * 16 + l16] = acc[mt][nt][r];
    if (l16 == 0) {
        #pragma unroll
        for (int mt = 0; mt < 4; ++mt)
            #pragma unroll
            for (int r = 0; r < 4; ++r)
                densp[((size_t)blockIdx.y * n + i0 + mt * 16 + q * 4 + r) * HEADS + wave] = accd[mt][r];
    }
}

// ============ normalize: out = sum_s outsp / sum_s densp ============
__global__ __launch_bounds__(256) void normalize(const float* __restrict__ outsp,
                                                 const float* __restrict__ densp,
                                                 float* __restrict__ out, int n, int splits) {
    const int g = blockIdx.x * 256 + threadIdx.x;
    const int i = g >> 6;
    const int c4 = (g & 63) * 4;
    const int head = c4 >> 6;
    float den = 0.f;
    for (int s = 0; s < splits; ++s) den += densp[((size_t)s * n + i) * HEADS + head];
    float4 v = {0.f, 0.f, 0.f, 0.f};
    for (int s = 0; s < splits; ++s) {
        const float4 t = *(const float4*)&outsp[(size_t)s * n * HD + (size_t)i * HD + c4];
        v.x += t.x; v.y += t.y; v.z += t.z; v.w += t.w;
    }
    const float inv = 1.0f / den;
    v.x *= inv; v.y *= inv; v.z *= inv; v.w *= inv;
    *(float4*)&out[(size_t)i * HD + c4] = v;
}

extern "C" void kernel_launch(void* const* d_in, const int* in_sizes, int n_in,
                              void* d_out, int out_size, void* d_ws, size_t ws_size,
                              hipStream_t stream) {
    const float* x   = (const float*)d_in[0];
    const int*   adj = (const int*)d_in[1];
    const float* W   = (const float*)d_in[2];
    const float* att = (const float*)d_in[3];
    float* out = (float*)d_out;

    const int in_dim = in_sizes[2] / HD;   // 256
    const int n = in_sizes[0] / in_dim;    // 4096

    char* ws = (char*)d_ws;
    size_t off = 0;
    auto alloc = [&](size_t bytes) -> void* {
        void* p = ws + off; off += (bytes + 255) & ~(size_t)255; return p;
    };
    __hip_bfloat16* xh = (__hip_bfloat16*)alloc((size_t)n * in_dim * 2);
    __hip_bfloat16* xl = (__hip_bfloat16*)alloc((size_t)n * in_dim * 2);
    __hip_bfloat16* wh = (__hip_bfloat16*)alloc((size_t)in_dim * HD * 2);
    __hip_bfloat16* wl = (__hip_bfloat16*)alloc((size_t)in_dim * HD * 2);
    float2*         Es = (float2*)alloc((size_t)HEADS * n * 8);
    float2*         Ed = (float2*)alloc((size_t)HEADS * n * 8);
    __hip_bfloat16* hbB = (__hip_bfloat16*)alloc((size_t)n * HD * 2);
    unsigned long long* adjP = (unsigned long long*)alloc((size_t)n * (n >> 6) * 8);

    const size_t outB = (size_t)n * HD * 4, denB = (size_t)n * HEADS * 4;
    // SPLITS=8 (512 blocks at i-tile 64) when workspace allows; fallback 4.
    int splits = SPLITS;
    if (ws_size && off + (size_t)splits * (((outB + 255) & ~(size_t)255) + ((denB + 255) & ~(size_t)255)) > ws_size)
        splits = 4;
    float* densp = (float*)alloc((size_t)splits * denB);
    float* outsp = (float*)alloc((size_t)splits * outB);

    const int nxb = (n / 16) * (in_dim / 32) * 64 / 256;
    const int nwb = (HD / 16) * (in_dim / 32) * 64 / 256;
    pack_xw<<<nxb + nwb, 256, 0, stream>>>(x, W, xh, xl, wh, wl, in_dim, nxb);
    adj_pack<<<1024, 256, 0, stream>>>(adj, adjP, n);
    gemm_fused<<<dim3(n / 32, HEADS), 128, 0, stream>>>(xh, xl, wh, wl, att, Es, Ed, hbB, n, in_dim);
    aggregate<<<dim3(n / 64, splits), 256, 0, stream>>>((const unsigned int*)adjP, Es, Ed,
                                                        hbB, outsp, densp, n, n / splits);
    normalize<<<n * 64 / 256, 256, 0, stream>>>(outsp, densp, out, n, splits);
}